// Round 4
// baseline (123.560 us; speedup 1.0000x reference)
//
#include <hip/hip_runtime.h>

typedef __bf16 bf16x8 __attribute__((ext_vector_type(8)));
typedef __bf16 bf16x4 __attribute__((ext_vector_type(4)));
typedef float floatx4 __attribute__((ext_vector_type(4)));
typedef float f32x2  __attribute__((ext_vector_type(2)));

#define NENT 237
#define NREL 237
#define D 128
#define B_TRIPLES 16384
#define LDSP 136  // 128 k-elements + 8 pad (272 B pitch -> benign 2-way aliasing on b128 reads)

// proj[r][e][j] = sum_d ent_emb[e][d] * rel_W[r][d][j]
// One block per (128-row slab, relation): 474 blocks x 256 threads.
// SINGLE-PHASE: stage full K=128 of E and W^T (69.6 KB LDS, 2 blocks/CU),
// ONE barrier, then 64 back-to-back MFMAs per wave.  16 outstanding dwordx4
// loads per thread cover HBM latency during staging; cross-block overlap
// covers the single barrier drain.
__global__ __launch_bounds__(256) void proj_gemm(
    const float* __restrict__ ent_emb,   // (N, 128) fp32, only rows <256 touched
    const float* __restrict__ rel_W,     // (237, 128, 128) fp32
    float* __restrict__ proj)            // (237, 237, 128) fp32 (workspace)
{
  const int r   = blockIdx.y;
  const int m0  = blockIdx.x * 128;      // 0 or 128
  const int tid = threadIdx.x;

  __shared__ __bf16 sE[128 * LDSP];      // A: sE[m][k]   (row-major, k contiguous)
  __shared__ __bf16 sW[128 * LDSP];      // B^T: sW[n][k] = W[k][n]

  const int wave = tid >> 6;
  const int lane = tid & 63;
  const int lrow = lane & 15;
  const int quad = lane >> 4;
  const int r0 = wave * 32;              // wave's 32-row stripe

  // --- stage E (fp32 -> bf16), 128 rows x 128 k: thread = (row, k-half) ---
  {
    const int row  = tid >> 1;           // 0..127
    const int half = (tid & 1) * 64;     // k sub-offset (64 floats per thread)
    const float* src = ent_emb + (size_t)(m0 + row) * D + half;
    __bf16* dst = sE + row * LDSP + half;
#pragma unroll
    for (int i = 0; i < 16; ++i) {
      float4 v = ((const float4*)src)[i];
      bf16x4 pk = { (__bf16)v.x, (__bf16)v.y, (__bf16)v.z, (__bf16)v.w };
      *(bf16x4*)(dst + i * 4) = pk;
    }
  }
  // --- stage W transposed (fp32 -> bf16): sW[n][k] = W[k][n] ---
  // lane-per-k mapping: write bank = (4n + k/2)%32 spans all 32 banks,
  // adjacent lanes (k, k+1) land in the same 4B word -> conflict-free.
  {
    const int k  = tid & 127;            // 0..127
    const int n0 = (tid >> 7) * 64;      // 0 or 64 (64 n-values per thread)
    const float* src = rel_W + ((size_t)r * D + k) * D + n0;
#pragma unroll
    for (int i = 0; i < 16; ++i) {
      float4 v = ((const float4*)src)[i];
      const int n = n0 + i * 4;
      sW[(n + 0) * LDSP + k] = (__bf16)v.x;
      sW[(n + 1) * LDSP + k] = (__bf16)v.y;
      sW[(n + 2) * LDSP + k] = (__bf16)v.z;
      sW[(n + 3) * LDSP + k] = (__bf16)v.w;
    }
  }
  __syncthreads();

  floatx4 acc[2][8];
#pragma unroll
  for (int tr = 0; tr < 2; ++tr)
#pragma unroll
    for (int tc = 0; tc < 8; ++tc)
      acc[tr][tc] = (floatx4){0.f, 0.f, 0.f, 0.f};

  // --- MFMA: 4 k-steps of 32, no intervening barriers ---
#pragma unroll
  for (int kk = 0; kk < 4; ++kk) {
    const int k0 = kk * 32 + quad * 8;
    bf16x8 a[2], b[8];
#pragma unroll
    for (int tr = 0; tr < 2; ++tr)
      a[tr] = *(const bf16x8*)&sE[(r0 + tr * 16 + lrow) * LDSP + k0];
#pragma unroll
    for (int tc = 0; tc < 8; ++tc)
      b[tc] = *(const bf16x8*)&sW[(tc * 16 + lrow) * LDSP + k0];
#pragma unroll
    for (int tr = 0; tr < 2; ++tr)
#pragma unroll
      for (int tc = 0; tc < 8; ++tc)
        acc[tr][tc] = __builtin_amdgcn_mfma_f32_16x16x32_bf16(
            a[tr], b[tc], acc[tr][tc], 0, 0, 0);
  }

  // --- store: D[m][n], m = quad*4 + reg (verified m89/m91 layout), n = lrow ---
#pragma unroll
  for (int tr = 0; tr < 2; ++tr) {
    const int ebase = m0 + r0 + tr * 16 + quad * 4;
#pragma unroll
    for (int reg = 0; reg < 4; ++reg) {
      const int e = ebase + reg;
      if (e < NENT) {
        float* dst = proj + ((size_t)r * NENT + e) * D;
#pragma unroll
        for (int tc = 0; tc < 8; ++tc)
          dst[tc * 16 + lrow] = acc[tr][tc][reg];
      }
    }
  }
}

// out[b] = fc_b + sum_{c,j} relu(w0[c]*ph[j] + w1[c]*re[j] + w2[c]*pt[j] + cb[c]) * fcw[c*128+j]
// TWO triples per wave: 12 gather loads issued together (2x MLP on L3 latency),
// one shared ds_read_b64 of fc_w feeds both triples, two independent FMA
// chains (ILP).  8192 waves keeps occupancy (LDS caps at 6 blocks/CU).
__global__ __launch_bounds__(256) void conv_fc(
    const int*   __restrict__ triples,   // (B,3)
    const float* __restrict__ rel_emb,   // (237,128)
    const float* __restrict__ conv_w,    // (50,3)
    const float* __restrict__ conv_b,    // (50)
    const float* __restrict__ fc_w,      // (6400)
    const float* __restrict__ fc_b,      // (1)
    const float* __restrict__ proj,      // (237,237,128)
    float*       __restrict__ out)       // (B,)
{
  const int tid  = threadIdx.x;
  const int wave = tid >> 6;
  const int lane = tid & 63;
  const int b0   = (blockIdx.x * 4 + wave) * 2;

  __shared__ float2 sFw[50 * 64];        // sFw[c*64+l] = {fc_w[c*128+l], fc_w[c*128+64+l]}

  // issue both triples' gathers first -- latency hides under fc_w staging
  const int h0 = triples[b0 * 3 + 0];
  const int r0 = triples[b0 * 3 + 1];
  const int t0 = triples[b0 * 3 + 2];
  const int h1 = triples[b0 * 3 + 3];
  const int r1 = triples[b0 * 3 + 4];
  const int t1 = triples[b0 * 3 + 5];
  const float* ph0p = proj + ((size_t)r0 * NENT + h0) * D;
  const float* pt0p = proj + ((size_t)r0 * NENT + t0) * D;
  const float* re0p = rel_emb + (size_t)r0 * D;
  const float* ph1p = proj + ((size_t)r1 * NENT + h1) * D;
  const float* pt1p = proj + ((size_t)r1 * NENT + t1) * D;
  const float* re1p = rel_emb + (size_t)r1 * D;
  f32x2 vph0 = { ph0p[lane], ph0p[lane + 64] };
  f32x2 vpt0 = { pt0p[lane], pt0p[lane + 64] };
  f32x2 vre0 = { re0p[lane], re0p[lane + 64] };
  f32x2 vph1 = { ph1p[lane], ph1p[lane + 64] };
  f32x2 vpt1 = { pt1p[lane], pt1p[lane + 64] };
  f32x2 vre1 = { re1p[lane], re1p[lane + 64] };

  // cooperative fc_w -> LDS (each wave owns c = wave, wave+4, ...)
  for (int c = wave; c < 50; c += 4)
    sFw[c * 64 + lane] = make_float2(fc_w[c * D + lane], fc_w[c * D + 64 + lane]);
  __syncthreads();

  f32x2 acc0 = (f32x2){0.f, 0.f};
  f32x2 acc1 = (f32x2){0.f, 0.f};
#pragma unroll
  for (int c = 0; c < 50; ++c) {
    const float w0 = conv_w[c * 3 + 0];
    const float w1 = conv_w[c * 3 + 1];
    const float w2 = conv_w[c * 3 + 2];
    const float bc = conv_b[c];
    const float2 fwc = sFw[c * 64 + lane];            // ds_read_b64, imm offset
    f32x2 f0 = vph0 * w0 + vre0 * w1 + vpt0 * w2 + bc;
    f32x2 f1 = vph1 * w0 + vre1 * w1 + vpt1 * w2 + bc;
    f0.x = fmaxf(f0.x, 0.f);  f0.y = fmaxf(f0.y, 0.f);
    f1.x = fmaxf(f1.x, 0.f);  f1.y = fmaxf(f1.y, 0.f);
    acc0.x = fmaf(f0.x, fwc.x, acc0.x);
    acc0.y = fmaf(f0.y, fwc.y, acc0.y);
    acc1.x = fmaf(f1.x, fwc.x, acc1.x);
    acc1.y = fmaf(f1.y, fwc.y, acc1.y);
  }
  float a0 = acc0.x + acc0.y;
  float a1 = acc1.x + acc1.y;
#pragma unroll
  for (int off = 32; off; off >>= 1) {
    a0 += __shfl_down(a0, off, 64);
    a1 += __shfl_down(a1, off, 64);
  }
  if (lane == 0) {
    const float fb = fc_b[0];
    out[b0]     = a0 + fb;
    out[b0 + 1] = a1 + fb;
  }
}

extern "C" void kernel_launch(void* const* d_in, const int* in_sizes, int n_in,
                              void* d_out, int out_size, void* d_ws, size_t ws_size,
                              hipStream_t stream) {
  const int*   triples = (const int*)  d_in[0];
  const float* ent_emb = (const float*)d_in[1];
  const float* rel_emb = (const float*)d_in[2];
  const float* rel_W   = (const float*)d_in[3];
  const float* conv_w  = (const float*)d_in[4];
  const float* conv_b  = (const float*)d_in[5];
  const float* fc_w    = (const float*)d_in[6];
  const float* fc_b    = (const float*)d_in[7];
  float* out  = (float*)d_out;
  float* proj = (float*)d_ws;            // 237*237*128 fp32 = 28.8 MB

  dim3 g1(2, NREL);
  proj_gemm<<<g1, 256, 0, stream>>>(ent_emb, rel_W, proj);
  conv_fc<<<B_TRIPLES / 8, 256, 0, stream>>>(triples, rel_emb, conv_w, conv_b,
                                             fc_w, fc_b, proj, out);
}